// Round 2
// baseline (548.247 us; speedup 1.0000x reference)
//
#include <hip/hip_runtime.h>

typedef unsigned short u16;
typedef u16 u16x4 __attribute__((ext_vector_type(4)));
typedef u16 u16x8 __attribute__((ext_vector_type(8)));
typedef __bf16 bf16x8 __attribute__((ext_vector_type(8)));
typedef float f32x4 __attribute__((ext_vector_type(4)));

#define GL2LDS(gp, lp)                                                          \
  __builtin_amdgcn_global_load_lds(                                             \
      (const __attribute__((address_space(1))) void*)(gp),                      \
      (__attribute__((address_space(3))) void*)(lp), 16, 0, 0)

__device__ __forceinline__ u16 f2bf(float f) {
  unsigned u = __builtin_bit_cast(unsigned, f);
  u += 0x7fffu + ((u >> 16) & 1u);
  return (u16)(u >> 16);
}

__device__ __forceinline__ float bf2f(u16 v) {
  unsigned u = ((unsigned)v) << 16;
  return __builtin_bit_cast(float, u);
}

__device__ __forceinline__ f32x4 mfma_bf16(u16x8 a, u16x8 b, f32x4 c) {
  return __builtin_amdgcn_mfma_f32_16x16x32_bf16(
      __builtin_bit_cast(bf16x8, a), __builtin_bit_cast(bf16x8, b), c, 0, 0, 0);
}

constexpr int BN_ = 8;      // batch
constexpr int S_ = 2048;    // seq
constexpr int D_ = 1024;    // embed

// ---------------------------------------------------------------- convert f32 -> bf16
__global__ __launch_bounds__(256) void cvt_bf16(const float* __restrict__ in,
                                                u16* __restrict__ out, int n8) {
  int i = blockIdx.x * blockDim.x + threadIdx.x;
  int stride = gridDim.x * blockDim.x;
  for (; i < n8; i += stride) {
    const float4* p = reinterpret_cast<const float4*>(in) + (size_t)i * 2;
    float4 a = p[0], b = p[1];
    u16x8 o;
    o[0] = f2bf(a.x); o[1] = f2bf(a.y); o[2] = f2bf(a.z); o[3] = f2bf(a.w);
    o[4] = f2bf(b.x); o[5] = f2bf(b.y); o[6] = f2bf(b.z); o[7] = f2bf(b.w);
    reinterpret_cast<u16x8*>(out)[i] = o;
  }
}

// ---------------------------------------------------------------- mask precompute
// msk[r][c] = bf16(rot[r][c]^2); rinv[r] = 1 / max(sum_c rot^2, EPS^2)
__global__ __launch_bounds__(256) void mask_kernel(const float* __restrict__ rot,
                                                   u16* __restrict__ msk,
                                                   float* __restrict__ rinv) {
  int r = blockIdx.x, t = threadIdx.x;
  const float4* p = reinterpret_cast<const float4*>(rot + (size_t)r * S_);
  float4 a = p[t], b = p[t + 256];
  float ax = a.x * a.x, ay = a.y * a.y, az = a.z * a.z, aw = a.w * a.w;
  float bx = b.x * b.x, by = b.y * b.y, bz = b.z * b.z, bw = b.w * b.w;
  u16x4 oa, ob;
  oa[0] = f2bf(ax); oa[1] = f2bf(ay); oa[2] = f2bf(az); oa[3] = f2bf(aw);
  ob[0] = f2bf(bx); ob[1] = f2bf(by); ob[2] = f2bf(bz); ob[3] = f2bf(bw);
  u16* mrow = msk + (size_t)r * S_;
  *reinterpret_cast<u16x4*>(mrow + t * 4) = oa;
  *reinterpret_cast<u16x4*>(mrow + 1024 + t * 4) = ob;
  float s = ax + ay + az + aw + bx + by + bz + bw;
#pragma unroll
  for (int d = 1; d < 64; d <<= 1) s += __shfl_xor(s, d);
  __shared__ float wsum[4];
  if ((t & 63) == 0) wsum[t >> 6] = s;
  __syncthreads();
  if (t == 0) {
    float ss = wsum[0] + wsum[1] + wsum[2] + wsum[3];
    rinv[r] = 1.0f / fmaxf(ss, 1e-24f);
  }
}

// ---------------------------------------------------------------- GEMM  C = A @ B^T
// A: M x K bf16 row-major; Bm: N x K bf16 row-major (K contiguous both).
// MODE 0: out bf16 [r*N+c] = acc + bias[c]                (q, k projections)
// MODE 1: out bf16 transposed per batch: vt[b][c][s]      (v projection)
// MODE 2: out fp32 [z][r*N+c] = acc * rinv[r] / Z[z][r]   (PV, batched via blockIdx.z)
template <int MODE>
__global__ __launch_bounds__(256)
void gemm_bt(const u16* __restrict__ A, const u16* __restrict__ Bm,
             const float* __restrict__ aux, const float* __restrict__ aux2,
             void* __restrict__ outp, int M, int N, int K) {
  __shared__ alignas(16) u16 As[4096];
  __shared__ alignas(16) u16 Bs[4096];
  const int t = threadIdx.x;
  const int lane = t & 63, w = t >> 6;
  const int wm = w >> 1, wn = w & 1;
  const int z = blockIdx.z;

  const u16* Ab = A + (MODE == 2 ? (size_t)z * S_ * S_ : 0);
  const u16* Bb = Bm + (MODE == 2 ? (size_t)z * D_ * S_ : 0);

  const int rowBase = blockIdx.y * 128;
  const int colBase = blockIdx.x * 128;

  const int srow = t >> 2, scol = (t & 3) * 8;
  const u16* gA = Ab + ((size_t)(rowBase + srow)) * K + scol;
  const u16* gB = Bb + ((size_t)(colBase + srow)) * K + scol;
  const size_t rstep = (size_t)64 * K;

  const int lr = lane & 15, lk = (lane >> 4) * 8;
  const u16* aRd = As + (wm * 64 + lr) * 32 + lk;
  const u16* bRd = Bs + (wn * 64 + lr) * 32 + lk;

  f32x4 acc[4][4] = {};
  const int nk = K >> 5;
  for (int kt = 0; kt < nk; ++kt) {
    __syncthreads();
    const int k0 = kt * 32;
    GL2LDS(gA + k0, As + t * 8);
    GL2LDS(gA + rstep + k0, As + 2048 + t * 8);
    GL2LDS(gB + k0, Bs + t * 8);
    GL2LDS(gB + rstep + k0, Bs + 2048 + t * 8);
    __syncthreads();
    u16x8 af[4], bfr[4];
#pragma unroll
    for (int i = 0; i < 4; ++i)
      af[i] = *reinterpret_cast<const u16x8*>(aRd + i * 16 * 32);
#pragma unroll
    for (int j = 0; j < 4; ++j)
      bfr[j] = *reinterpret_cast<const u16x8*>(bRd + j * 16 * 32);
#pragma unroll
    for (int i = 0; i < 4; ++i)
#pragma unroll
      for (int j = 0; j < 4; ++j)
        acc[i][j] = mfma_bf16(af[i], bfr[j], acc[i][j]);
  }

  const int lrow4 = (lane >> 4) * 4;
  const int lcol = lane & 15;
  if constexpr (MODE == 0) {
    float bias[4];
#pragma unroll
    for (int j = 0; j < 4; ++j) bias[j] = aux[colBase + wn * 64 + j * 16 + lcol];
    u16* out16 = (u16*)outp;
#pragma unroll
    for (int i = 0; i < 4; ++i) {
#pragma unroll
      for (int jj = 0; jj < 4; ++jj) {
        int r = rowBase + wm * 64 + i * 16 + lrow4 + jj;
#pragma unroll
        for (int j = 0; j < 4; ++j) {
          int c = colBase + wn * 64 + j * 16 + lcol;
          out16[(size_t)r * N + c] = f2bf(acc[i][j][jj] + bias[j]);
        }
      }
    }
  } else if constexpr (MODE == 1) {
    // transpose through LDS, then coalesced column writes: vt[b][c][s]
    __shared__ u16 Ts[128][136];
    float bias[4];
#pragma unroll
    for (int j = 0; j < 4; ++j) bias[j] = aux[colBase + wn * 64 + j * 16 + lcol];
#pragma unroll
    for (int i = 0; i < 4; ++i)
#pragma unroll
      for (int jj = 0; jj < 4; ++jj)
#pragma unroll
        for (int j = 0; j < 4; ++j)
          Ts[wn * 64 + j * 16 + lcol][wm * 64 + i * 16 + lrow4 + jj] =
              f2bf(acc[i][j][jj] + bias[j]);
    __syncthreads();
    const int b = rowBase >> 11, s0 = rowBase & (S_ - 1);
    const int cl = t >> 1, so = (t & 1) * 64;
    u16* dst = (u16*)outp + (size_t)b * D_ * S_ + (size_t)(colBase + cl) * S_ + s0 + so;
    const u16* src = &Ts[cl][so];
#pragma unroll
    for (int k2 = 0; k2 < 8; ++k2)
      *reinterpret_cast<u16x8*>(dst + k2 * 8) =
          *reinterpret_cast<const u16x8*>(src + k2 * 8);
  } else {
    float* outf = (float*)outp + (size_t)z * S_ * D_;
    const float* Zb = aux + (size_t)z * S_;
#pragma unroll
    for (int i = 0; i < 4; ++i) {
#pragma unroll
      for (int jj = 0; jj < 4; ++jj) {
        int r = rowBase + wm * 64 + i * 16 + lrow4 + jj;
        float rz = aux2[r] / Zb[r];
#pragma unroll
        for (int j = 0; j < 4; ++j) {
          int c = colBase + wn * 64 + j * 16 + lcol;
          outf[(size_t)r * N + c] = acc[i][j][jj] * rz;
        }
      }
    }
  }
}

// ---------------------------------------------------------------- scores kernel
// For (b, q-tile of 128, k-split of 256 cols): logits = q @ k^T / 32;
// hyb = exp(l) * msk (bf16, unnormalized); Z[b,row] += sum_k exp(l).
__global__ __launch_bounds__(256)
void score_kernel(const u16* __restrict__ qb, const u16* __restrict__ kb,
                  const u16* __restrict__ msk, u16* __restrict__ hyb,
                  float* __restrict__ Z) {
  __shared__ alignas(16) u16 As[4096];
  __shared__ alignas(16) u16 Bs[4096];
  const int t = threadIdx.x;
  const int lane = t & 63, w = t >> 6;
  const int wm = w >> 1, wn = w & 1;
  const int ks = blockIdx.x, qt = blockIdx.y, b = blockIdx.z;
  const int q0 = qt * 128;

  const int srow = t >> 2, scol = (t & 3) * 8;
  const u16* gA = qb + ((size_t)(b * S_ + q0 + srow)) * D_ + scol;
  const size_t rstep = (size_t)64 * D_;

  const int lr = lane & 15, lk = (lane >> 4) * 8;
  const u16* aRd = As + (wm * 64 + lr) * 32 + lk;
  const u16* bRd = Bs + (wn * 64 + lr) * 32 + lk;
  const int lrow4 = (lane >> 4) * 4;
  const int lcol = lane & 15;

  float zacc[4][4] = {};

  for (int t2 = 0; t2 < 2; ++t2) {
    const int kc0 = ks * 256 + t2 * 128;
    const u16* gB = kb + ((size_t)(b * S_ + kc0 + srow)) * D_ + scol;
    f32x4 acc[4][4] = {};
    for (int kt = 0; kt < 32; ++kt) {
      __syncthreads();
      const int k0 = kt * 32;
      GL2LDS(gA + k0, As + t * 8);
      GL2LDS(gA + rstep + k0, As + 2048 + t * 8);
      GL2LDS(gB + k0, Bs + t * 8);
      GL2LDS(gB + rstep + k0, Bs + 2048 + t * 8);
      __syncthreads();
      u16x8 af[4], bfr[4];
#pragma unroll
      for (int i = 0; i < 4; ++i)
        af[i] = *reinterpret_cast<const u16x8*>(aRd + i * 16 * 32);
#pragma unroll
      for (int j = 0; j < 4; ++j)
        bfr[j] = *reinterpret_cast<const u16x8*>(bRd + j * 16 * 32);
#pragma unroll
      for (int i = 0; i < 4; ++i)
#pragma unroll
        for (int j = 0; j < 4; ++j)
          acc[i][j] = mfma_bf16(af[i], bfr[j], acc[i][j]);
    }
    // epilogue for this 128x128 logits tile
#pragma unroll
    for (int i = 0; i < 4; ++i) {
#pragma unroll
      for (int jj = 0; jj < 4; ++jj) {
        const int row = q0 + wm * 64 + i * 16 + lrow4 + jj;
        const size_t hrow = ((size_t)(b * S_ + row)) * S_;
        const size_t mrow = (size_t)row * S_;
#pragma unroll
        for (int j = 0; j < 4; ++j) {
          const int col = kc0 + wn * 64 + j * 16 + lcol;
          float e = __expf(acc[i][j][jj] * 0.03125f);
          hyb[hrow + col] = f2bf(e * bf2f(msk[mrow + col]));
          zacc[i][jj] += e;
        }
      }
    }
  }

  // reduce Z across the 16 column-lanes, then atomically accumulate per row
#pragma unroll
  for (int i = 0; i < 4; ++i)
#pragma unroll
    for (int jj = 0; jj < 4; ++jj) {
      float v = zacc[i][jj];
#pragma unroll
      for (int d = 1; d < 16; d <<= 1) v += __shfl_xor(v, d);
      if ((lane & 15) == 0) {
        int row = q0 + wm * 64 + i * 16 + lrow4 + jj;
        atomicAdd(&Z[b * S_ + row], v);
      }
    }
}

// ---------------------------------------------------------------- launch
extern "C" void kernel_launch(void* const* d_in, const int* in_sizes, int n_in,
                              void* d_out, int out_size, void* d_ws, size_t ws_size,
                              hipStream_t stream) {
  const float* x = (const float*)d_in[0];
  const float* Wq = (const float*)d_in[1];
  const float* bq = (const float*)d_in[2];
  const float* Wk = (const float*)d_in[3];
  const float* bk = (const float*)d_in[4];
  const float* Wv = (const float*)d_in[5];
  const float* bv = (const float*)d_in[6];
  const float* rot = (const float*)d_in[7];

  char* ws = (char*)d_ws;
  size_t off = 0;
  auto take = [&](size_t bytes) {
    char* p = ws + off;
    off += (bytes + 255) & ~(size_t)255;
    return p;
  };
  u16* xb = (u16*)take((size_t)BN_ * S_ * D_ * 2);        // 32 MB
  u16* wqb = (u16*)take((size_t)D_ * D_ * 2);             // 2 MB
  u16* wkb = (u16*)take((size_t)D_ * D_ * 2);
  u16* wvb = (u16*)take((size_t)D_ * D_ * 2);
  u16* qb = (u16*)take((size_t)BN_ * S_ * D_ * 2);        // 32 MB
  u16* kb = (u16*)take((size_t)BN_ * S_ * D_ * 2);        // 32 MB
  u16* vtb = (u16*)take((size_t)BN_ * S_ * D_ * 2);       // 32 MB (B,D,S)
  u16* hyb = (u16*)take((size_t)BN_ * S_ * S_ * 2);       // 64 MB
  u16* msk = (u16*)take((size_t)S_ * S_ * 2);             // 8.4 MB
  float* Zb = (float*)take((size_t)BN_ * S_ * 4);
  float* rinv = (float*)take((size_t)S_ * 4);

  hipMemsetAsync(Zb, 0, (size_t)BN_ * S_ * 4, stream);

  cvt_bf16<<<2048, 256, 0, stream>>>(x, xb, BN_ * S_ * D_ / 8);
  cvt_bf16<<<512, 256, 0, stream>>>(Wq, wqb, D_ * D_ / 8);
  cvt_bf16<<<512, 256, 0, stream>>>(Wk, wkb, D_ * D_ / 8);
  cvt_bf16<<<512, 256, 0, stream>>>(Wv, wvb, D_ * D_ / 8);
  mask_kernel<<<S_, 256, 0, stream>>>(rot, msk, rinv);

  const int M = BN_ * S_;  // 16384
  gemm_bt<0><<<dim3(D_ / 128, M / 128, 1), 256, 0, stream>>>(xb, wqb, bq, nullptr, qb, M, D_, D_);
  gemm_bt<0><<<dim3(D_ / 128, M / 128, 1), 256, 0, stream>>>(xb, wkb, bk, nullptr, kb, M, D_, D_);
  gemm_bt<1><<<dim3(D_ / 128, M / 128, 1), 256, 0, stream>>>(xb, wvb, bv, nullptr, vtb, M, D_, D_);

  score_kernel<<<dim3(8, S_ / 128, BN_), 256, 0, stream>>>(qb, kb, msk, hyb, Zb);

  gemm_bt<2><<<dim3(D_ / 128, S_ / 128, BN_), 256, 0, stream>>>(hyb, vtb, Zb, rinv, d_out,
                                                                S_, D_, S_);
}

// Round 4
// 412.292 us; speedup vs baseline: 1.3298x; 1.3298x over previous
//
#include <hip/hip_runtime.h>

typedef unsigned short u16;
typedef u16 u16x4 __attribute__((ext_vector_type(4)));
typedef u16 u16x8 __attribute__((ext_vector_type(8)));
typedef __bf16 bf16x8 __attribute__((ext_vector_type(8)));
typedef float f32x4 __attribute__((ext_vector_type(4)));

#define GL2LDS(gp, lp)                                                          \
  __builtin_amdgcn_global_load_lds(                                             \
      (const __attribute__((address_space(1))) void*)(gp),                      \
      (__attribute__((address_space(3))) void*)(lp), 16, 0, 0)

__device__ __forceinline__ u16 f2bf(float f) {
  unsigned u = __builtin_bit_cast(unsigned, f);
  u += 0x7fffu + ((u >> 16) & 1u);
  return (u16)(u >> 16);
}

__device__ __forceinline__ float bf2f(u16 v) {
  unsigned u = ((unsigned)v) << 16;
  return __builtin_bit_cast(float, u);
}

__device__ __forceinline__ f32x4 mfma_bf16(u16x8 a, u16x8 b, f32x4 c) {
  return __builtin_amdgcn_mfma_f32_16x16x32_bf16(
      __builtin_bit_cast(bf16x8, a), __builtin_bit_cast(bf16x8, b), c, 0, 0, 0);
}

constexpr int BN_ = 8;      // batch
constexpr int S_ = 2048;    // seq
constexpr int D_ = 1024;    // embed

// ---------------------------------------------------------------- convert f32 -> bf16
__global__ __launch_bounds__(256) void cvt_bf16(const float* __restrict__ in,
                                                u16* __restrict__ out, int n8) {
  int i = blockIdx.x * blockDim.x + threadIdx.x;
  int stride = gridDim.x * blockDim.x;
  for (; i < n8; i += stride) {
    const float4* p = reinterpret_cast<const float4*>(in) + (size_t)i * 2;
    float4 a = p[0], b = p[1];
    u16x8 o;
    o[0] = f2bf(a.x); o[1] = f2bf(a.y); o[2] = f2bf(a.z); o[3] = f2bf(a.w);
    o[4] = f2bf(b.x); o[5] = f2bf(b.y); o[6] = f2bf(b.z); o[7] = f2bf(b.w);
    reinterpret_cast<u16x8*>(out)[i] = o;
  }
}

// ---------------------------------------------------------------- bias concat
__global__ __launch_bounds__(256) void concat3(const float* __restrict__ a,
                                               const float* __restrict__ b,
                                               const float* __restrict__ c,
                                               float* __restrict__ o) {
  int i = blockIdx.x * 256 + threadIdx.x;
  if (i < 1024) o[i] = a[i];
  else if (i < 2048) o[i] = b[i - 1024];
  else if (i < 3072) o[i] = c[i - 2048];
}

// ---------------------------------------------------------------- mask precompute
// msk[r][c] = bf16(rot[r][c]^2); rinv[r] = 1 / max(sum_c rot^2, EPS^2)
__global__ __launch_bounds__(256) void mask_kernel(const float* __restrict__ rot,
                                                   u16* __restrict__ msk,
                                                   float* __restrict__ rinv) {
  int r = blockIdx.x, t = threadIdx.x;
  const float4* p = reinterpret_cast<const float4*>(rot + (size_t)r * S_);
  float4 a = p[t], b = p[t + 256];
  float ax = a.x * a.x, ay = a.y * a.y, az = a.z * a.z, aw = a.w * a.w;
  float bx = b.x * b.x, by = b.y * b.y, bz = b.z * b.z, bw = b.w * b.w;
  u16x4 oa, ob;
  oa[0] = f2bf(ax); oa[1] = f2bf(ay); oa[2] = f2bf(az); oa[3] = f2bf(aw);
  ob[0] = f2bf(bx); ob[1] = f2bf(by); ob[2] = f2bf(bz); ob[3] = f2bf(bw);
  u16* mrow = msk + (size_t)r * S_;
  *reinterpret_cast<u16x4*>(mrow + t * 4) = oa;
  *reinterpret_cast<u16x4*>(mrow + 1024 + t * 4) = ob;
  float s = ax + ay + az + aw + bx + by + bz + bw;
#pragma unroll
  for (int d = 1; d < 64; d <<= 1) s += __shfl_xor(s, d);
  __shared__ float wsum[4];
  if ((t & 63) == 0) wsum[t >> 6] = s;
  __syncthreads();
  if (t == 0) {
    float ss = wsum[0] + wsum[1] + wsum[2] + wsum[3];
    rinv[r] = 1.0f / fmaxf(ss, 1e-24f);
  }
}

// ---------------------------------------------------------------- fused QKV GEMM
// C = xb @ wcat^T + bcat ; cols 0-1023 -> qb, 1024-2047 -> kb, 2048-3071 -> vtb (transposed)
// 2-phase double-buffered pipeline: stage(next) issued before compute(cur).
__global__ __launch_bounds__(256)
void gemm_qkv(const u16* __restrict__ xb, const u16* __restrict__ wcat,
              const float* __restrict__ bcat, u16* __restrict__ qb,
              u16* __restrict__ kb, u16* __restrict__ vtb) {
  __shared__ alignas(16) u16 pool[17408];  // 2 bufs x (A 4096 | B 4096); Ts aliases
  const int t = threadIdx.x;
  const int lane = t & 63, w = t >> 6;
  const int wm = w >> 1, wn = w & 1;
  const int rowBase = blockIdx.y * 128;
  const int colBase = blockIdx.x * 128;
  const int srow = t >> 2, scol = (t & 3) * 8;
  const u16* gA = xb + ((size_t)(rowBase + srow)) * D_ + scol;
  const u16* gB = wcat + ((size_t)(colBase + srow)) * D_ + scol;
  const size_t rstep = (size_t)64 * D_;
  const int lr = lane & 15, lk = (lane >> 4) * 8;
  const int aOff = (wm * 64 + lr) * 32 + lk;
  const int bOff = 4096 + (wn * 64 + lr) * 32 + lk;

  auto stage = [&](int buf, int k0) {
    u16* d = pool + buf * 8192;
    GL2LDS(gA + k0, d + t * 8);
    GL2LDS(gA + rstep + k0, d + 2048 + t * 8);
    GL2LDS(gB + k0, d + 4096 + t * 8);
    GL2LDS(gB + rstep + k0, d + 6144 + t * 8);
  };

  f32x4 acc[4][4] = {};
  stage(0, 0);
  int cur = 0;
  for (int kt = 0; kt < 32; ++kt) {
    __syncthreads();  // cur buf staged; previous reads done
    if (kt < 31) stage(cur ^ 1, (kt + 1) * 32);
    const u16* base = pool + cur * 8192;
    u16x8 af[4], bfr[4];
#pragma unroll
    for (int i = 0; i < 4; ++i)
      af[i] = *reinterpret_cast<const u16x8*>(base + aOff + i * 16 * 32);
#pragma unroll
    for (int j = 0; j < 4; ++j)
      bfr[j] = *reinterpret_cast<const u16x8*>(base + bOff + j * 16 * 32);
#pragma unroll
    for (int i = 0; i < 4; ++i)
#pragma unroll
      for (int j = 0; j < 4; ++j)
        acc[i][j] = mfma_bf16(af[i], bfr[j], acc[i][j]);
    cur ^= 1;
  }

  const int lrow4 = (lane >> 4) * 4, lcol = lane & 15;
  float bias[4];
#pragma unroll
  for (int j = 0; j < 4; ++j) bias[j] = bcat[colBase + wn * 64 + j * 16 + lcol];
  const int cls = colBase >> 10;     // 0=q, 1=k, 2=v
  const int ccol = colBase & 1023;
  if (cls < 2) {
    u16* out16 = (cls == 0) ? qb : kb;
#pragma unroll
    for (int i = 0; i < 4; ++i) {
#pragma unroll
      for (int jj = 0; jj < 4; ++jj) {
        int r = rowBase + wm * 64 + i * 16 + lrow4 + jj;
#pragma unroll
        for (int j = 0; j < 4; ++j) {
          int c = ccol + wn * 64 + j * 16 + lcol;
          out16[(size_t)r * D_ + c] = f2bf(acc[i][j][jj] + bias[j]);
        }
      }
    }
  } else {
    // v: transpose through LDS (aliases staging pool), coalesced column writes
    __syncthreads();  // all LDS reads of the K-loop done before overwrite
    u16 (*Ts)[136] = reinterpret_cast<u16(*)[136]>(pool);
#pragma unroll
    for (int i = 0; i < 4; ++i)
#pragma unroll
      for (int jj = 0; jj < 4; ++jj)
#pragma unroll
        for (int j = 0; j < 4; ++j)
          Ts[wn * 64 + j * 16 + lcol][wm * 64 + i * 16 + lrow4 + jj] =
              f2bf(acc[i][j][jj] + bias[j]);
    __syncthreads();
    const int b = rowBase >> 11, s0 = rowBase & (S_ - 1);
    const int cl = t >> 1, so = (t & 1) * 64;
    u16* dst = vtb + (size_t)b * D_ * S_ + (size_t)(ccol + cl) * S_ + s0 + so;
    const u16* src = &Ts[cl][so];
#pragma unroll
    for (int k2 = 0; k2 < 8; ++k2)
      *reinterpret_cast<u16x8*>(dst + k2 * 8) =
          *reinterpret_cast<const u16x8*>(src + k2 * 8);
  }
}

// ---------------------------------------------------------------- scores kernel
// block lin: ks = lin&7 (XCD affinity: per-XCD k-slice+msk-slice L2-resident),
// b = (lin>>3)&7, qt = lin>>6. Two 128x128 tiles per block; 2-phase pipeline;
// next tile's first stage issued before the epilogue (hides refill under exp/stores).
__global__ __launch_bounds__(256)
void score_kernel(const u16* __restrict__ qb, const u16* __restrict__ kb,
                  const u16* __restrict__ msk, u16* __restrict__ hyb,
                  float* __restrict__ Z) {
  __shared__ alignas(16) u16 pool[16384];
  const int t = threadIdx.x;
  const int lane = t & 63, w = t >> 6;
  const int wm = w >> 1, wn = w & 1;
  const int lin = blockIdx.x;
  const int ks = lin & 7, b = (lin >> 3) & 7, qt = lin >> 6;
  const int q0 = qt * 128;

  const int srow = t >> 2, scol = (t & 3) * 8;
  const u16* gA = qb + ((size_t)(b * S_ + q0 + srow)) * D_ + scol;
  const size_t rstep = (size_t)64 * D_;
  const int lr = lane & 15, lk = (lane >> 4) * 8;
  const int aOff = (wm * 64 + lr) * 32 + lk;
  const int bOff = 4096 + (wn * 64 + lr) * 32 + lk;
  const int lrow4 = (lane >> 4) * 4;
  const int lcol = lane & 15;

  auto stage = [&](int buf, int t2, int k0) {
    u16* d = pool + buf * 8192;
    const u16* gB = kb + ((size_t)(b * S_ + ks * 256 + t2 * 128 + srow)) * D_ + scol;
    GL2LDS(gA + k0, d + t * 8);
    GL2LDS(gA + rstep + k0, d + 2048 + t * 8);
    GL2LDS(gB + k0, d + 4096 + t * 8);
    GL2LDS(gB + rstep + k0, d + 6144 + t * 8);
  };

  float zacc[4][4] = {};
  stage(0, 0, 0);
  int cur = 0;
  for (int t2 = 0; t2 < 2; ++t2) {
    f32x4 acc[4][4] = {};
    for (int kt = 0; kt < 32; ++kt) {
      __syncthreads();
      if (kt < 31) stage(cur ^ 1, t2, (kt + 1) * 32);
      else if (t2 == 0) stage(cur ^ 1, 1, 0);
      const u16* base = pool + cur * 8192;
      u16x8 af[4], bfr[4];
#pragma unroll
      for (int i = 0; i < 4; ++i)
        af[i] = *reinterpret_cast<const u16x8*>(base + aOff + i * 16 * 32);
#pragma unroll
      for (int j = 0; j < 4; ++j)
        bfr[j] = *reinterpret_cast<const u16x8*>(base + bOff + j * 16 * 32);
#pragma unroll
      for (int i = 0; i < 4; ++i)
#pragma unroll
        for (int j = 0; j < 4; ++j)
          acc[i][j] = mfma_bf16(af[i], bfr[j], acc[i][j]);
      cur ^= 1;
    }
    // epilogue for this 128x128 logits tile (no LDS use — overlaps next tile's loads)
    const int kc0 = ks * 256 + t2 * 128;
#pragma unroll
    for (int i = 0; i < 4; ++i) {
#pragma unroll
      for (int jj = 0; jj < 4; ++jj) {
        const int row = q0 + wm * 64 + i * 16 + lrow4 + jj;
        const size_t hrow = ((size_t)(b * S_ + row)) * S_;
        const size_t mrow = (size_t)row * S_;
#pragma unroll
        for (int j = 0; j < 4; ++j) {
          const int col = kc0 + wn * 64 + j * 16 + lcol;
          float e = __expf(acc[i][j][jj] * 0.03125f);
          hyb[hrow + col] = f2bf(e * bf2f(msk[mrow + col]));
          zacc[i][jj] += e;
        }
      }
    }
  }

  // reduce Z across the 16 column-lanes, then atomically accumulate per row
#pragma unroll
  for (int i = 0; i < 4; ++i)
#pragma unroll
    for (int jj = 0; jj < 4; ++jj) {
      float v = zacc[i][jj];
#pragma unroll
      for (int d = 1; d < 16; d <<= 1) v += __shfl_xor(v, d);
      if ((lane & 15) == 0) {
        int row = q0 + wm * 64 + i * 16 + lrow4 + jj;
        atomicAdd(&Z[b * S_ + row], v);
      }
    }
}

// ---------------------------------------------------------------- PV GEMM
// out[z] = (hyb[z] @ vtb[z]^T-layout) * rinv[r] / Z[z][r]; 2-phase pipeline.
__global__ __launch_bounds__(256)
void gemm_pv(const u16* __restrict__ hyb, const u16* __restrict__ vtb,
             const float* __restrict__ Z, const float* __restrict__ rinv,
             float* __restrict__ outp) {
  __shared__ alignas(16) u16 pool[16384];
  const int t = threadIdx.x;
  const int lane = t & 63, w = t >> 6;
  const int wm = w >> 1, wn = w & 1;
  const int z = blockIdx.z;
  const int rowBase = blockIdx.y * 128;
  const int colBase = blockIdx.x * 128;
  const int K = S_;
  const u16* Ab = hyb + (size_t)z * S_ * S_;
  const u16* Bb = vtb + (size_t)z * D_ * S_;
  const int srow = t >> 2, scol = (t & 3) * 8;
  const u16* gA = Ab + ((size_t)(rowBase + srow)) * K + scol;
  const u16* gB = Bb + ((size_t)(colBase + srow)) * K + scol;
  const size_t rstep = (size_t)64 * K;
  const int lr = lane & 15, lk = (lane >> 4) * 8;
  const int aOff = (wm * 64 + lr) * 32 + lk;
  const int bOff = 4096 + (wn * 64 + lr) * 32 + lk;

  auto stage = [&](int buf, int k0) {
    u16* d = pool + buf * 8192;
    GL2LDS(gA + k0, d + t * 8);
    GL2LDS(gA + rstep + k0, d + 2048 + t * 8);
    GL2LDS(gB + k0, d + 4096 + t * 8);
    GL2LDS(gB + rstep + k0, d + 6144 + t * 8);
  };

  f32x4 acc[4][4] = {};
  stage(0, 0);
  int cur = 0;
  const int nk = K >> 5;  // 64
  for (int kt = 0; kt < nk; ++kt) {
    __syncthreads();
    if (kt + 1 < nk) stage(cur ^ 1, (kt + 1) * 32);
    const u16* base = pool + cur * 8192;
    u16x8 af[4], bfr[4];
#pragma unroll
    for (int i = 0; i < 4; ++i)
      af[i] = *reinterpret_cast<const u16x8*>(base + aOff + i * 16 * 32);
#pragma unroll
    for (int j = 0; j < 4; ++j)
      bfr[j] = *reinterpret_cast<const u16x8*>(base + bOff + j * 16 * 32);
#pragma unroll
    for (int i = 0; i < 4; ++i)
#pragma unroll
      for (int j = 0; j < 4; ++j)
        acc[i][j] = mfma_bf16(af[i], bfr[j], acc[i][j]);
    cur ^= 1;
  }

  const int lrow4 = (lane >> 4) * 4, lcol = lane & 15;
  float* outf = outp + (size_t)z * S_ * D_;
  const float* Zb = Z + (size_t)z * S_;
#pragma unroll
  for (int i = 0; i < 4; ++i) {
#pragma unroll
    for (int jj = 0; jj < 4; ++jj) {
      int r = rowBase + wm * 64 + i * 16 + lrow4 + jj;
      float rz = rinv[r] / Zb[r];
#pragma unroll
      for (int j = 0; j < 4; ++j) {
        int c = colBase + wn * 64 + j * 16 + lcol;
        outf[(size_t)r * D_ + c] = acc[i][j][jj] * rz;
      }
    }
  }
}

// ---------------------------------------------------------------- launch
extern "C" void kernel_launch(void* const* d_in, const int* in_sizes, int n_in,
                              void* d_out, int out_size, void* d_ws, size_t ws_size,
                              hipStream_t stream) {
  const float* x = (const float*)d_in[0];
  const float* Wq = (const float*)d_in[1];
  const float* bq = (const float*)d_in[2];
  const float* Wk = (const float*)d_in[3];
  const float* bk = (const float*)d_in[4];
  const float* Wv = (const float*)d_in[5];
  const float* bv = (const float*)d_in[6];
  const float* rot = (const float*)d_in[7];

  char* ws = (char*)d_ws;
  size_t off = 0;
  auto take = [&](size_t bytes) {
    char* p = ws + off;
    off += (bytes + 255) & ~(size_t)255;
    return p;
  };
  u16* xb = (u16*)take((size_t)BN_ * S_ * D_ * 2);        // 32 MB
  u16* wcat = (u16*)take((size_t)3 * D_ * D_ * 2);        // 6 MB (Wq|Wk|Wv)
  float* bcat = (float*)take((size_t)3 * D_ * 4);
  u16* qb = (u16*)take((size_t)BN_ * S_ * D_ * 2);        // 32 MB
  u16* kb = (u16*)take((size_t)BN_ * S_ * D_ * 2);        // 32 MB
  u16* vtb = (u16*)take((size_t)BN_ * S_ * D_ * 2);       // 32 MB (B,D,S)
  u16* hyb = (u16*)take((size_t)BN_ * S_ * S_ * 2);       // 64 MB
  u16* msk = (u16*)take((size_t)S_ * S_ * 2);             // 8.4 MB
  float* Zb = (float*)take((size_t)BN_ * S_ * 4);
  float* rinv = (float*)take((size_t)S_ * 4);

  (void)hipMemsetAsync(Zb, 0, (size_t)BN_ * S_ * 4, stream);

  cvt_bf16<<<2048, 256, 0, stream>>>(x, xb, BN_ * S_ * D_ / 8);
  cvt_bf16<<<512, 256, 0, stream>>>(Wq, wcat, D_ * D_ / 8);
  cvt_bf16<<<512, 256, 0, stream>>>(Wk, wcat + (size_t)D_ * D_, D_ * D_ / 8);
  cvt_bf16<<<512, 256, 0, stream>>>(Wv, wcat + (size_t)2 * D_ * D_, D_ * D_ / 8);
  concat3<<<12, 256, 0, stream>>>(bq, bk, bv, bcat);
  mask_kernel<<<S_, 256, 0, stream>>>(rot, msk, rinv);

  const int M = BN_ * S_;  // 16384
  gemm_qkv<<<dim3(3 * D_ / 128, M / 128), 256, 0, stream>>>(xb, wcat, bcat, qb, kb, vtb);

  score_kernel<<<dim3(8 * 8 * (S_ / 128)), 256, 0, stream>>>(qb, kb, msk, hyb, Zb);

  gemm_pv<<<dim3(D_ / 128, S_ / 128, BN_), 256, 0, stream>>>(hyb, vtb, Zb, rinv,
                                                             (float*)d_out);
}

// Round 5
// 302.618 us; speedup vs baseline: 1.8117x; 1.3624x over previous
//
#include <hip/hip_runtime.h>

typedef unsigned short u16;
typedef u16 u16x4 __attribute__((ext_vector_type(4)));
typedef u16 u16x8 __attribute__((ext_vector_type(8)));
typedef __bf16 bf16x8 __attribute__((ext_vector_type(8)));
typedef float f32x4 __attribute__((ext_vector_type(4)));

#define GL2LDS(gp, lp)                                                          \
  __builtin_amdgcn_global_load_lds(                                             \
      (const __attribute__((address_space(1))) void*)(gp),                      \
      (__attribute__((address_space(3))) void*)(lp), 16, 0, 0)

__device__ __forceinline__ u16 f2bf(float f) {
  unsigned u = __builtin_bit_cast(unsigned, f);
  u += 0x7fffu + ((u >> 16) & 1u);
  return (u16)(u >> 16);
}

__device__ __forceinline__ float bf2f(u16 v) {
  unsigned u = ((unsigned)v) << 16;
  return __builtin_bit_cast(float, u);
}

__device__ __forceinline__ f32x4 mfma_bf16(u16x8 a, u16x8 b, f32x4 c) {
  return __builtin_amdgcn_mfma_f32_16x16x32_bf16(
      __builtin_bit_cast(bf16x8, a), __builtin_bit_cast(bf16x8, b), c, 0, 0, 0);
}

constexpr int BN_ = 8;      // batch
constexpr int S_ = 2048;    // seq
constexpr int D_ = 1024;    // embed

// ---------------------------------------------------------------- small kernels
__global__ __launch_bounds__(256) void cvt_bf16(const float* __restrict__ in,
                                                u16* __restrict__ out, int n8) {
  int i = blockIdx.x * blockDim.x + threadIdx.x;
  int stride = gridDim.x * blockDim.x;
  for (; i < n8; i += stride) {
    const float4* p = reinterpret_cast<const float4*>(in) + (size_t)i * 2;
    float4 a = p[0], b = p[1];
    u16x8 o;
    o[0] = f2bf(a.x); o[1] = f2bf(a.y); o[2] = f2bf(a.z); o[3] = f2bf(a.w);
    o[4] = f2bf(b.x); o[5] = f2bf(b.y); o[6] = f2bf(b.z); o[7] = f2bf(b.w);
    reinterpret_cast<u16x8*>(out)[i] = o;
  }
}

__global__ __launch_bounds__(256) void concat3(const float* __restrict__ a,
                                               const float* __restrict__ b,
                                               const float* __restrict__ c,
                                               float* __restrict__ o) {
  int i = blockIdx.x * 256 + threadIdx.x;
  if (i < 1024) o[i] = a[i];
  else if (i < 2048) o[i] = b[i - 1024];
  else if (i < 3072) o[i] = c[i - 2048];
}

// msk[r][c] = bf16(rot[r][c]^2); rinv[r] = 1 / max(sum_c rot^2, EPS^2)
__global__ __launch_bounds__(256) void mask_kernel(const float* __restrict__ rot,
                                                   u16* __restrict__ msk,
                                                   float* __restrict__ rinv) {
  int r = blockIdx.x, t = threadIdx.x;
  const float4* p = reinterpret_cast<const float4*>(rot + (size_t)r * S_);
  float4 a = p[t], b = p[t + 256];
  float ax = a.x * a.x, ay = a.y * a.y, az = a.z * a.z, aw = a.w * a.w;
  float bx = b.x * b.x, by = b.y * b.y, bz = b.z * b.z, bw = b.w * b.w;
  u16x4 oa, ob;
  oa[0] = f2bf(ax); oa[1] = f2bf(ay); oa[2] = f2bf(az); oa[3] = f2bf(aw);
  ob[0] = f2bf(bx); ob[1] = f2bf(by); ob[2] = f2bf(bz); ob[3] = f2bf(bw);
  u16* mrow = msk + (size_t)r * S_;
  *reinterpret_cast<u16x4*>(mrow + t * 4) = oa;
  *reinterpret_cast<u16x4*>(mrow + 1024 + t * 4) = ob;
  float s = ax + ay + az + aw + bx + by + bz + bw;
#pragma unroll
  for (int d = 1; d < 64; d <<= 1) s += __shfl_xor(s, d);
  __shared__ float wsum[4];
  if ((t & 63) == 0) wsum[t >> 6] = s;
  __syncthreads();
  if (t == 0) {
    float ss = wsum[0] + wsum[1] + wsum[2] + wsum[3];
    rinv[r] = 1.0f / fmaxf(ss, 1e-24f);
  }
}

// ---------------------------------------------------------------- 8-phase K-loop core
// 256x256 tile, BK=64, 8 waves (2M x 4N), per-wave C = 128x64.
// LDS: 2 buffers x {A,B} x {k0,k1} regions of [256 rows][32 cols] u16 (16 KB each).
// Swizzle: 16B-slot index sl ^= 2*(row bit3)  (st_16x32 family); applied as
// inverse-swizzled GLOBAL source on stage + swizzled ds_read address (linear DMA dest).
// Schedule per iteration (2 K-tiles kb,kb+1): 8 phases, each stages exactly one
// half-region released at the previous phase boundary; vmcnt(6) at phases 4,8 only.
template <int NK>
__device__ __forceinline__ void kloop8(const u16* __restrict__ Abase,
                                       const u16* __restrict__ Bbase,
                                       int sA, int sB, u16* sh,
                                       f32x4 (&acc)[8][4]) {
  const int t = threadIdx.x;
  const int lane = t & 63, w = t >> 6;
  const int wm = w >> 2, wn = w & 3;
  const int lr = lane & 15;
  const int sl = (lane >> 4) ^ (((lr >> 3) & 1) << 1);   // swizzled 16B slot
  const int aOff = (wm * 128 + lr) * 32 + sl * 8;        // u16, within (P,kk) region
  const int bOff = 16384 + (wn * 64 + lr) * 32 + sl * 8; // + B-op offset

  // stage source precompute (inverse swizzle on global address)
  const int tr = t ^ (((t >> 5) & 1) << 1);
  const u16* aSrc = Abase + (size_t)(tr >> 2) * sA + (tr & 3) * 8;
  const u16* bSrc = Bbase + (size_t)(tr >> 2) * sB + (tr & 3) * 8;
  const size_t a128 = (size_t)128 * sA, b128 = (size_t)128 * sB;
  u16* dBase = sh + t * 8;

  auto stage = [&](int P, int op, int kk, int kt) {
    kt &= (NK - 1);  // wrap at tail: uniform vmcnt counting, data unused
    const u16* s = (op ? bSrc : aSrc) + kt * 64 + kk * 32;
    u16* d = dBase + P * 32768 + op * 16384 + kk * 8192;
    GL2LDS(s, d);
    GL2LDS(s + (op ? b128 : a128), d + 4096);
  };

  u16x8 bf[4];

#define PHASE(P, kk, mh, sP, sOp, sKk, sKt, vm)                                  \
  do {                                                                           \
    const u16* ap_ = sh + (P) * 32768 + (kk) * 8192 + aOff;                      \
    u16x8 af_[4];                                                                \
    _Pragma("unroll")                                                            \
    for (int i_ = 0; i_ < 4; ++i_)                                               \
      af_[i_] = *reinterpret_cast<const u16x8*>(ap_ + ((mh) * 4 + i_) * 512);    \
    if ((mh) == 0) {                                                             \
      const u16* bp_ = sh + (P) * 32768 + (kk) * 8192 + bOff;                    \
      _Pragma("unroll")                                                          \
      for (int j_ = 0; j_ < 4; ++j_)                                             \
        bf[j_] = *reinterpret_cast<const u16x8*>(bp_ + j_ * 512);                \
    }                                                                            \
    stage(sP, sOp, sKk, sKt);                                                    \
    asm volatile("s_barrier" ::: "memory");                                      \
    __builtin_amdgcn_s_setprio(1);                                               \
    _Pragma("unroll")                                                            \
    for (int i_ = 0; i_ < 4; ++i_)                                               \
      _Pragma("unroll")                                                          \
      for (int j_ = 0; j_ < 4; ++j_)                                             \
        acc[(mh) * 4 + i_][j_] = mfma_bf16(af_[i_], bf[j_], acc[(mh) * 4 + i_][j_]); \
    __builtin_amdgcn_s_setprio(0);                                               \
    if (vm) asm volatile("s_waitcnt vmcnt(6)" ::: "memory");                     \
    asm volatile("s_barrier" ::: "memory");                                      \
  } while (0)

  // prologue: K0 fully, K1 all but A.k1 (staged by ph1); allow last 3 stages in flight
  stage(0, 1, 0, 0); stage(0, 0, 0, 0); stage(0, 1, 1, 0); stage(0, 0, 1, 0);
  stage(1, 1, 0, 1); stage(1, 0, 0, 1); stage(1, 1, 1, 1);
  asm volatile("s_waitcnt vmcnt(6)" ::: "memory");
  asm volatile("s_barrier" ::: "memory");

  for (int j2 = 0; j2 < NK / 2; ++j2) {
    const int kb = 2 * j2;
    PHASE(0, 0, 0, 1, 0, 1, kb + 1, false);  // stage P1.A.k1 <- ktile kb+1
    PHASE(0, 0, 1, 0, 1, 0, kb + 2, false);  // stage P0.B.k0 <- kb+2
    PHASE(0, 1, 0, 0, 0, 0, kb + 2, false);  // stage P0.A.k0 <- kb+2
    PHASE(0, 1, 1, 0, 1, 1, kb + 2, true);   // stage P0.B.k1 <- kb+2, vmcnt(6)
    PHASE(1, 0, 0, 0, 0, 1, kb + 2, false);  // stage P0.A.k1 <- kb+2
    PHASE(1, 0, 1, 1, 1, 0, kb + 3, false);  // stage P1.B.k0 <- kb+3
    PHASE(1, 1, 0, 1, 0, 0, kb + 3, false);  // stage P1.A.k0 <- kb+3
    PHASE(1, 1, 1, 1, 1, 1, kb + 3, true);   // stage P1.B.k1 <- kb+3, vmcnt(6)
  }
#undef PHASE
}

// ---------------------------------------------------------------- fused QKV (256^2, 8-phase)
// C = xb @ wcat^T + bcat; col-tiles 0-3 -> q, 4-7 -> k, 8-11 -> v (transposed to vt)
__global__ __launch_bounds__(512, 2)
void gemm_qkv8(const u16* __restrict__ xb, const u16* __restrict__ wcat,
               const float* __restrict__ bcat, u16* __restrict__ qb,
               u16* __restrict__ kb, u16* __restrict__ vtb) {
  __shared__ alignas(16) u16 sh[65536];
  const int lin = blockIdx.x;
  const int swz = (lin & 7) * 96 + (lin >> 3);   // 768 blocks, 8 XCDs
  const int rt = swz / 12, ct = swz - rt * 12;
  const int rowBase = rt << 8, colBase = ct << 8;

  f32x4 acc[8][4] = {};
  kloop8<16>(xb + (size_t)rowBase * D_, wcat + (size_t)colBase * D_, D_, D_, sh, acc);

  const int t = threadIdx.x;
  const int lane = t & 63, w = t >> 6;
  const int wm = w >> 2, wn = w & 3;
  const int lrow4 = (lane >> 4) * 4, lcol = lane & 15;

  float bias[4];
#pragma unroll
  for (int j = 0; j < 4; ++j) bias[j] = bcat[colBase + wn * 64 + j * 16 + lcol];

  const int cls = colBase >> 10;  // 0=q, 1=k, 2=v
  const int ccol = colBase & 1023;
  if (cls < 2) {
    u16* out16 = (cls == 0) ? qb : kb;
#pragma unroll
    for (int i = 0; i < 8; ++i) {
#pragma unroll
      for (int jj = 0; jj < 4; ++jj) {
        int r = rowBase + wm * 128 + i * 16 + lrow4 + jj;
#pragma unroll
        for (int j = 0; j < 4; ++j) {
          int c = ccol + wn * 64 + j * 16 + lcol;
          out16[(size_t)r * D_ + c] = f2bf(acc[i][j][jj] + bias[j]);
        }
      }
    }
  } else {
    // v: transpose 256x256 tile through LDS in two 128-row passes
    __syncthreads();  // drains vmcnt(0): in-flight wrap-stage junk lands before reuse
    u16 (*Ts)[136] = reinterpret_cast<u16(*)[136]>(sh);
    const int bq = rowBase >> 11, s0 = rowBase & (S_ - 1);
#pragma unroll
    for (int h = 0; h < 2; ++h) {
      if (wm == h) {
#pragma unroll
        for (int i = 0; i < 8; ++i)
#pragma unroll
          for (int jj = 0; jj < 4; ++jj)
#pragma unroll
            for (int j = 0; j < 4; ++j)
              Ts[wn * 64 + j * 16 + lcol][i * 16 + lrow4 + jj] =
                  f2bf(acc[i][j][jj] + bias[j]);
      }
      __syncthreads();
      const int col = t >> 1, ro = (t & 1) * 64;
      u16* dst = vtb + (size_t)bq * D_ * S_ + (size_t)(ccol + col) * S_ +
                 s0 + h * 128 + ro;
      const u16* srcp = &Ts[col][ro];
#pragma unroll
      for (int k2 = 0; k2 < 8; ++k2)
        *reinterpret_cast<u16x8*>(dst + k2 * 8) =
            *reinterpret_cast<const u16x8*>(srcp + k2 * 8);
      __syncthreads();
    }
  }
}

// ---------------------------------------------------------------- scores (256^2, 8-phase)
// logits = q @ k^T / 32; hyb = exp(l)*msk (bf16, unnormalized); Z[b,row] += sum exp(l)
__global__ __launch_bounds__(512, 2)
void score8(const u16* __restrict__ qb, const u16* __restrict__ kb,
            const u16* __restrict__ msk, u16* __restrict__ hyb,
            float* __restrict__ Z) {
  __shared__ alignas(16) u16 sh[65536];
  const int lin = blockIdx.x;
  const int swz = (lin & 7) * 64 + (lin >> 3);   // 512 blocks; one batch per XCD
  const int b = swz >> 6, rt = (swz >> 3) & 7, ct = swz & 7;
  const int rowBase = rt << 8, colBase = ct << 8;

  f32x4 acc[8][4] = {};
  kloop8<16>(qb + ((size_t)(b * S_ + rowBase)) * D_,
             kb + ((size_t)(b * S_ + colBase)) * D_, D_, D_, sh, acc);

  const int t = threadIdx.x;
  const int lane = t & 63, w = t >> 6;
  const int wm = w >> 2, wn = w & 3;
  const int lrow4 = (lane >> 4) * 4, lcol = lane & 15;

#pragma unroll
  for (int i = 0; i < 8; ++i) {
    const int rowL = rowBase + wm * 128 + i * 16 + lrow4;
    f32x4 zrow = {0.f, 0.f, 0.f, 0.f};
#pragma unroll
    for (int j = 0; j < 4; ++j) {
      const int col = colBase + wn * 64 + j * 16 + lcol;
#pragma unroll
      for (int jj = 0; jj < 4; ++jj) {
        const int row = rowL + jj;
        float e = __expf(acc[i][j][jj] * 0.03125f);
        hyb[((size_t)(b * S_ + row)) * S_ + col] =
            f2bf(e * bf2f(msk[(size_t)row * S_ + col]));
        zrow[jj] += e;
      }
    }
#pragma unroll
    for (int d = 1; d < 16; d <<= 1) {
      zrow[0] += __shfl_xor(zrow[0], d);
      zrow[1] += __shfl_xor(zrow[1], d);
      zrow[2] += __shfl_xor(zrow[2], d);
      zrow[3] += __shfl_xor(zrow[3], d);
    }
    if (lcol == 0) {
#pragma unroll
      for (int jj = 0; jj < 4; ++jj)
        atomicAdd(&Z[b * S_ + rowL + jj], zrow[jj]);
    }
  }
}

// ---------------------------------------------------------------- PV (256^2, 8-phase)
// out[b] = (hyb[b] @ vt[b]^T-layout) * rinv[r] / Z[b][r]
__global__ __launch_bounds__(512, 2)
void gemm_pv8(const u16* __restrict__ hyb, const u16* __restrict__ vtb,
              const float* __restrict__ Z, const float* __restrict__ rinv,
              float* __restrict__ outp) {
  __shared__ alignas(16) u16 sh[65536];
  const int lin = blockIdx.x;
  const int swz = (lin & 7) * 32 + (lin >> 3);   // 256 blocks; one batch per XCD
  const int b = swz >> 5, rt = (swz >> 2) & 7, ct = swz & 3;
  const int rowBase = rt << 8, colBase = ct << 8;

  f32x4 acc[8][4] = {};
  kloop8<32>(hyb + (size_t)b * S_ * S_ + (size_t)rowBase * S_,
             vtb + (size_t)b * D_ * S_ + (size_t)colBase * S_, S_, S_, sh, acc);

  const int t = threadIdx.x;
  const int lane = t & 63, w = t >> 6;
  const int wm = w >> 2, wn = w & 3;
  const int lrow4 = (lane >> 4) * 4, lcol = lane & 15;

  float* outf = outp + (size_t)b * S_ * D_;
  const float* Zb = Z + (size_t)b * S_;
#pragma unroll
  for (int i = 0; i < 8; ++i) {
#pragma unroll
    for (int jj = 0; jj < 4; ++jj) {
      int r = rowBase + wm * 128 + i * 16 + lrow4 + jj;
      float rz = rinv[r] / Zb[r];
#pragma unroll
      for (int j = 0; j < 4; ++j) {
        int c = colBase + wn * 64 + j * 16 + lcol;
        outf[(size_t)r * D_ + c] = acc[i][j][jj] * rz;
      }
    }
  }
}

// ---------------------------------------------------------------- launch
extern "C" void kernel_launch(void* const* d_in, const int* in_sizes, int n_in,
                              void* d_out, int out_size, void* d_ws, size_t ws_size,
                              hipStream_t stream) {
  const float* x = (const float*)d_in[0];
  const float* Wq = (const float*)d_in[1];
  const float* bq = (const float*)d_in[2];
  const float* Wk = (const float*)d_in[3];
  const float* bk = (const float*)d_in[4];
  const float* Wv = (const float*)d_in[5];
  const float* bv = (const float*)d_in[6];
  const float* rot = (const float*)d_in[7];

  char* ws = (char*)d_ws;
  size_t off = 0;
  auto take = [&](size_t bytes) {
    char* p = ws + off;
    off += (bytes + 255) & ~(size_t)255;
    return p;
  };
  u16* xb = (u16*)take((size_t)BN_ * S_ * D_ * 2);        // 32 MB
  u16* wcat = (u16*)take((size_t)3 * D_ * D_ * 2);        // 6 MB (Wq|Wk|Wv)
  float* bcat = (float*)take((size_t)3 * D_ * 4);
  u16* qb = (u16*)take((size_t)BN_ * S_ * D_ * 2);        // 32 MB
  u16* kbuf = (u16*)take((size_t)BN_ * S_ * D_ * 2);      // 32 MB
  u16* vtb = (u16*)take((size_t)BN_ * S_ * D_ * 2);       // 32 MB (B,D,S)
  u16* hyb = (u16*)take((size_t)BN_ * S_ * S_ * 2);       // 64 MB
  u16* msk = (u16*)take((size_t)S_ * S_ * 2);             // 8.4 MB
  float* Zb = (float*)take((size_t)BN_ * S_ * 4);
  float* rinv = (float*)take((size_t)S_ * 4);

  (void)hipMemsetAsync(Zb, 0, (size_t)BN_ * S_ * 4, stream);

  cvt_bf16<<<2048, 256, 0, stream>>>(x, xb, BN_ * S_ * D_ / 8);
  cvt_bf16<<<512, 256, 0, stream>>>(Wq, wcat, D_ * D_ / 8);
  cvt_bf16<<<512, 256, 0, stream>>>(Wk, wcat + (size_t)D_ * D_, D_ * D_ / 8);
  cvt_bf16<<<512, 256, 0, stream>>>(Wv, wcat + (size_t)2 * D_ * D_, D_ * D_ / 8);
  concat3<<<12, 256, 0, stream>>>(bq, bk, bv, bcat);
  mask_kernel<<<S_, 256, 0, stream>>>(rot, msk, rinv);

  gemm_qkv8<<<768, 512, 0, stream>>>(xb, wcat, bcat, qb, kbuf, vtb);

  score8<<<512, 512, 0, stream>>>(qb, kbuf, msk, hyb, Zb);

  gemm_pv8<<<256, 512, 0, stream>>>(hyb, vtb, Zb, rinv, (float*)d_out);
}